// Round 7
// baseline (1643.543 us; speedup 1.0000x reference)
//
#include <hip/hip_runtime.h>

// NGCF forward, MI355X. Sizes fixed by the problem.
constexpr int N_NODES = 300000;   // N_USERS + N_ITEMS
constexpr int DIM = 64;

// Bucketed CSR build parameters
constexpr int CHUNK  = 8192;            // edges per binning block
constexpr int B_ROWS = 256;             // rows per bucket (bucket = row >> 8)
constexpr int NB_B   = (N_NODES + B_ROWS - 1) / B_ROWS;   // 1172 buckets
constexpr int CAP    = 12288;           // max edges/bucket in bucketfinal LDS
constexpr int SCAN_B = 4096;            // elements per scan1 block (16/thread)
constexpr int COL_MASK = (1 << 19) - 1; // col < 2^19 (300000 < 524288)

typedef unsigned short ushort_t;

__device__ __forceinline__ float blo(unsigned u) { return __uint_as_float(u << 16); }
__device__ __forceinline__ float bhi(unsigned u) { return __uint_as_float(u & 0xffff0000u); }
__device__ __forceinline__ ushort_t f2b(float f) {            // fp32 -> bf16 (RNE)
    unsigned u = __float_as_uint(f);
    return (ushort_t)((u + 0x7fffu + ((u >> 16) & 1u)) >> 16);
}

// ---------------------------------------------------------------------------
// k1: per-chunk bucket histogram. histT[chunk][b] (coalesced write).
// ---------------------------------------------------------------------------
__global__ __launch_bounds__(256) void binhist_kernel(
    const int* __restrict__ rows, int* __restrict__ histT, int nnz)
{
    __shared__ int cnt[NB_B];
    for (int i = threadIdx.x; i < NB_B; i += 256) cnt[i] = 0;
    __syncthreads();
    int base = blockIdx.x * CHUNK;
#pragma unroll
    for (int k = 0; k < CHUNK / 256; ++k) {
        int e = base + k * 256 + threadIdx.x;
        if (e < nnz) atomicAdd(&cnt[rows[e] >> 8], 1);
    }
    __syncthreads();
    for (int b = threadIdx.x; b < NB_B; b += 256)
        histT[(size_t)blockIdx.x * NB_B + b] = cnt[b];
}

// 32x32 tiled transpose: in[R][C] -> out[C][R]
__global__ __launch_bounds__(256) void transpose_kernel(
    const int* __restrict__ in, int* __restrict__ out, int R, int C)
{
    __shared__ int tile[32][33];
    int c0 = blockIdx.x * 32, r0 = blockIdx.y * 32;
    int tx = threadIdx.x & 31, ty = threadIdx.x >> 5;
#pragma unroll
    for (int k = 0; k < 4; ++k) {
        int r = r0 + ty + k * 8, c = c0 + tx;
        if (r < R && c < C) tile[ty + k * 8][tx] = in[(size_t)r * C + c];
    }
    __syncthreads();
#pragma unroll
    for (int k = 0; k < 4; ++k) {
        int c = c0 + ty + k * 8, r = r0 + tx;
        if (c < C && r < R) out[(size_t)c * R + r] = tile[tx][ty + k * 8];
    }
}

// ---------------------------------------------------------------------------
// Exclusive scan over n elements (in place).
// ---------------------------------------------------------------------------
__global__ __launch_bounds__(256) void scan1_kernel(
    int* __restrict__ a, int* __restrict__ bsum, int n)
{
    __shared__ int tsum[256];
    int base = blockIdx.x * SCAN_B;
    int v[16];
    int s = 0;
#pragma unroll
    for (int k = 0; k < 16; ++k) {
        int i = base + threadIdx.x * 16 + k;
        v[k] = (i < n) ? a[i] : 0;
        s += v[k];
    }
    tsum[threadIdx.x] = s;
    __syncthreads();
    for (int off = 1; off < 256; off <<= 1) {
        int u = (threadIdx.x >= off) ? tsum[threadIdx.x - off] : 0;
        __syncthreads();
        tsum[threadIdx.x] += u;
        __syncthreads();
    }
    int excl = (threadIdx.x == 0) ? 0 : tsum[threadIdx.x - 1];
#pragma unroll
    for (int k = 0; k < 16; ++k) {
        int i = base + threadIdx.x * 16 + k;
        if (i < n) a[i] = excl;
        excl += v[k];
    }
    if (threadIdx.x == 255) bsum[blockIdx.x] = tsum[255];
}

__global__ __launch_bounds__(256) void scan2_kernel(int* bsum, int nb)   // nb <= 2048
{
    __shared__ int tsum[256];
    int v[8];
    int s = 0;
#pragma unroll
    for (int k = 0; k < 8; ++k) {
        int i = threadIdx.x * 8 + k;
        v[k] = (i < nb) ? bsum[i] : 0;
        s += v[k];
    }
    tsum[threadIdx.x] = s;
    __syncthreads();
    for (int off = 1; off < 256; off <<= 1) {
        int u = (threadIdx.x >= off) ? tsum[threadIdx.x - off] : 0;
        __syncthreads();
        tsum[threadIdx.x] += u;
        __syncthreads();
    }
    int excl = (threadIdx.x == 0) ? 0 : tsum[threadIdx.x - 1];
#pragma unroll
    for (int k = 0; k < 8; ++k) {
        int i = threadIdx.x * 8 + k;
        if (i < nb) bsum[i] = excl;
        excl += v[k];
    }
}

__global__ __launch_bounds__(256) void scan3_kernel(
    int* __restrict__ a, const int* __restrict__ bsum, int n)
{
    int i = blockIdx.x * 256 + threadIdx.x;
    if (i < n) a[i] += bsum[i >> 12];    // SCAN_B = 4096
}

// ---------------------------------------------------------------------------
// k5: binned scatter — LDS counting-sort of the chunk, then ordered flush.
// Payload packed: x = col | (local_row << 19), y = val bits.
// ---------------------------------------------------------------------------
__global__ __launch_bounds__(512) void binscatter_kernel(
    const int* __restrict__ rows, const int* __restrict__ cols,
    const float* __restrict__ vals, const int* __restrict__ curT,
    int2* __restrict__ meta, int nnz)
{
    __shared__ int2 cv[CHUNK];      // 64 KB  sorted payload
    __shared__ int  dst[CHUNK];     // 32 KB  global destination per slot
    __shared__ int  cnt[NB_B];      // hist, then per-bucket cursor
    __shared__ int  loc[NB_B];      // local exclusive offsets
    __shared__ int  gb[NB_B];       // global bases for this chunk
    __shared__ int  tsum[512];

    const int tid  = threadIdx.x;
    const int base = blockIdx.x * CHUNK;

    for (int b = tid; b < NB_B; b += 512) cnt[b] = 0;
    __syncthreads();

    int rb[16], pk[16], vb[16];
#pragma unroll
    for (int k = 0; k < 16; ++k) {
        int e = base + k * 512 + tid;
        if (e < nnz) {
            int r = rows[e];
            rb[k] = r >> 8;
            pk[k] = cols[e] | ((r & 255) << 19);
            vb[k] = __float_as_int(vals[e]);
            atomicAdd(&cnt[rb[k]], 1);
        } else rb[k] = -1;
    }
    __syncthreads();

    int i0 = tid * 3;
    int c0 = 0, c1 = 0, c2 = 0, s = 0;
    if (i0     < NB_B) { c0 = cnt[i0];     s += c0; }
    if (i0 + 1 < NB_B) { c1 = cnt[i0 + 1]; s += c1; }
    if (i0 + 2 < NB_B) { c2 = cnt[i0 + 2]; s += c2; }
    tsum[tid] = s;
    __syncthreads();
    for (int off = 1; off < 512; off <<= 1) {
        int u = (tid >= off) ? tsum[tid - off] : 0;
        __syncthreads();
        tsum[tid] += u;
        __syncthreads();
    }
    int ex = (tid == 0) ? 0 : tsum[tid - 1];
    if (i0     < NB_B) { loc[i0]     = ex; ex += c0; }
    if (i0 + 1 < NB_B) { loc[i0 + 1] = ex; ex += c1; }
    if (i0 + 2 < NB_B) { loc[i0 + 2] = ex; ex += c2; }
    __syncthreads();

    for (int b = tid; b < NB_B; b += 512) {
        gb[b]  = curT[(size_t)blockIdx.x * NB_B + b];
        cnt[b] = 0;
    }
    __syncthreads();

#pragma unroll
    for (int k = 0; k < 16; ++k) {
        if (rb[k] >= 0) {
            int b   = rb[k];
            int off = atomicAdd(&cnt[b], 1);
            int p   = loc[b] + off;
            cv[p]   = make_int2(pk[k], vb[k]);
            dst[p]  = gb[b] + off;
        }
    }
    __syncthreads();

    int n = min(nnz - base, CHUNK);
    for (int i = tid; i < n; i += 512)
        meta[dst[i]] = cv[i];
}

// ---------------------------------------------------------------------------
// k6: per-bucket finalize. Builds row_ptr, permutes payload in place.
// ---------------------------------------------------------------------------
__global__ __launch_bounds__(256) void bucketfinal_kernel(
    const int* __restrict__ histS,      // [NB_B][nch] scanned (bucket-major)
    int2* __restrict__ meta,
    int* __restrict__ row_ptr, int nnz, int nch)
{
    __shared__ int2 cv[CAP];            // 96 KB
    __shared__ int cnt[256], scn[256], cur[256];

    int b    = blockIdx.x;
    int base = histS[(size_t)b * nch];
    int end  = (b + 1 < gridDim.x) ? histS[(size_t)(b + 1) * nch] : nnz;
    int n    = min(end - base, CAP);

    cnt[threadIdx.x] = 0;
    __syncthreads();
    for (int i = threadIdx.x; i < n; i += 256) {
        int2 m = meta[base + i];
        cv[i] = m;
        atomicAdd(&cnt[(m.x >> 19) & 255], 1);
    }
    __syncthreads();
    int v = cnt[threadIdx.x];
    scn[threadIdx.x] = v;
    __syncthreads();
    for (int off = 1; off < 256; off <<= 1) {
        int u = (threadIdx.x >= off) ? scn[threadIdx.x - off] : 0;
        __syncthreads();
        scn[threadIdx.x] += u;
        __syncthreads();
    }
    int excl = scn[threadIdx.x] - v;

    int r0 = b * B_ROWS;
    int nr = min(B_ROWS, N_NODES - r0);
    if (threadIdx.x < nr) row_ptr[r0 + threadIdx.x] = base + excl;
    if (b == gridDim.x - 1 && threadIdx.x == 0) row_ptr[N_NODES] = nnz;

    cur[threadIdx.x] = excl;
    __syncthreads();
    for (int i = threadIdx.x; i < n; i += 256) {
        int2 m = cv[i];
        int d = atomicAdd(&cur[(m.x >> 19) & 255], 1);
        meta[base + d] = m;
    }
}

// ---------------------------------------------------------------------------
// emb prep: out[:,0:64] = emb AND bf16 table in one pass over emb.
// ---------------------------------------------------------------------------
__global__ __launch_bounds__(256) void emb_prep_kernel(
    const float4* __restrict__ emb, ushort4* __restrict__ tblB,
    float4* __restrict__ out)
{
    int i = blockIdx.x * 256 + threadIdx.x;
    if (i >= N_NODES * 16) return;
    float4 x = emb[i];
    int n = i >> 4, j = i & 15;
    out[(size_t)n * 48 + j] = x;
    ushort4 u;
    u.x = f2b(x.x); u.y = f2b(x.y); u.z = f2b(x.z); u.w = f2b(x.w);
    tblB[i] = u;
}

// ---------------------------------------------------------------------------
// FUSED layer kernel: CSR gather-reduce (one wave per row) + dense transform
// + leaky_relu + row-norm + outputs. No side round-trip, no atomics.
//  - 8 edge slots (g) x 8 dim-eighths (q); fp32 accumulate; xor-reduce.
//  - g==0 lanes stage sv=s+e, pv=s*e into 512B wave-private LDS.
//  - dense: 32 b128 broadcast reads + bf16-packed per-lane weight registers
//    (64 VGPR instead of 128 -> 4 waves/SIMD).
// ---------------------------------------------------------------------------
template<bool WRITE_TBL>
__global__ __launch_bounds__(256, 3) void fused_layer_kernel(
    const uint4* __restrict__ tbl,      // bf16 gather table [N*8]
    const int*   __restrict__ row_ptr,
    const int2*  __restrict__ meta,
    const float* __restrict__ gw, const float* __restrict__ gb,
    const float* __restrict__ bw, const float* __restrict__ bb,
    ushort_t* __restrict__ tbl_out,     // bf16 ego out (layer 0 only)
    float* __restrict__ out, int out_col)
{
    __shared__ float svrow[4][DIM];
    __shared__ float pvrow[4][DIM];

    const int o  = threadIdx.x & 63;    // output dim owned by this lane
    const int wv = threadIdx.x >> 6;    // wave in block
    const int g  = o >> 3, q = o & 7;
    const int nwaves = gridDim.x << 2;

    // per-lane weights, packed bf16x2: w0p[2k+h] = (w[o][4k+2h+1], w[o][4k+2h])
    unsigned w0p[DIM / 2], w1p[DIM / 2];
#pragma unroll
    for (int k4 = 0; k4 < DIM / 4; ++k4) {
        float4 a = *(const float4*)(gw + (size_t)o * DIM + k4 * 4);
        float4 b = *(const float4*)(bw + (size_t)o * DIM + k4 * 4);
        w0p[2*k4]   = ((unsigned)f2b(a.y) << 16) | f2b(a.x);
        w0p[2*k4+1] = ((unsigned)f2b(a.w) << 16) | f2b(a.z);
        w1p[2*k4]   = ((unsigned)f2b(b.y) << 16) | f2b(b.x);
        w1p[2*k4+1] = ((unsigned)f2b(b.w) << 16) | f2b(b.z);
    }
    const float bias = gb[o] + bb[o];

    for (int row = blockIdx.x * 4 + wv; row < N_NODES; row += nwaves) {
        int start = row_ptr[row];
        int end   = row_ptr[row + 1];

        // ---- gather-reduce side row ----
        float acc[8];
#pragma unroll
        for (int i = 0; i < 8; ++i) acc[i] = 0.f;
        for (int j = start + g; j < end; j += 8) {
            int2 m = meta[j];
            float v = __int_as_float(m.y);
            uint4 x = tbl[(size_t)(m.x & COL_MASK) * 8 + q];
            acc[0] += v * blo(x.x); acc[1] += v * bhi(x.x);
            acc[2] += v * blo(x.y); acc[3] += v * bhi(x.y);
            acc[4] += v * blo(x.z); acc[5] += v * bhi(x.z);
            acc[6] += v * blo(x.w); acc[7] += v * bhi(x.w);
        }
#pragma unroll
        for (int off = 8; off <= 32; off <<= 1) {
#pragma unroll
            for (int i = 0; i < 8; ++i) acc[i] += __shfl_xor(acc[i], off);
        }

        // ---- stage sv, pv (g==0 lanes own dims q*8..q*8+7) ----
        if (g == 0) {
            uint4 eb = tbl[(size_t)row * 8 + q];
            float e0=blo(eb.x), e1=bhi(eb.x), e2=blo(eb.y), e3=bhi(eb.y);
            float e4=blo(eb.z), e5=bhi(eb.z), e6=blo(eb.w), e7=bhi(eb.w);
            float4* sd = (float4*)&svrow[wv][q * 8];
            float4* pd = (float4*)&pvrow[wv][q * 8];
            sd[0] = make_float4(acc[0]+e0, acc[1]+e1, acc[2]+e2, acc[3]+e3);
            sd[1] = make_float4(acc[4]+e4, acc[5]+e5, acc[6]+e6, acc[7]+e7);
            pd[0] = make_float4(acc[0]*e0, acc[1]*e1, acc[2]*e2, acc[3]*e3);
            pd[1] = make_float4(acc[4]*e4, acc[5]*e5, acc[6]*e6, acc[7]*e7);
        }
        __builtin_amdgcn_wave_barrier();   // order LDS writes before reads

        // ---- dense: y[o] = bias + sum_k sv[k]*gw[o][k] + pv[k]*bw[o][k] ----
        float a0 = bias, a1 = 0.f, a2 = 0.f, a3 = 0.f;
        const float4* s4 = (const float4*)&svrow[wv][0];
        const float4* p4 = (const float4*)&pvrow[wv][0];
#pragma unroll
        for (int k4 = 0; k4 < 16; ++k4) {
            float4 sk = s4[k4];            // all-lane broadcast reads
            float4 pk = p4[k4];
            unsigned u0 = w0p[2*k4], u1 = w0p[2*k4+1];
            unsigned v0 = w1p[2*k4], v1 = w1p[2*k4+1];
            a0 = fmaf(sk.x, blo(u0), a0);  a1 = fmaf(pk.x, blo(v0), a1);
            a2 = fmaf(sk.y, bhi(u0), a2);  a3 = fmaf(pk.y, bhi(v0), a3);
            a0 = fmaf(sk.z, blo(u1), a0);  a1 = fmaf(pk.z, blo(v1), a1);
            a2 = fmaf(sk.w, bhi(u1), a2);  a3 = fmaf(pk.w, bhi(v1), a3);
        }
        __builtin_amdgcn_wave_barrier();   // keep next-iter writes after reads

        float accv = (a0 + a1) + (a2 + a3);
        float y = accv > 0.f ? accv : 0.2f * accv;   // leaky_relu(0.2)
        if (WRITE_TBL) tbl_out[(size_t)row * DIM + o] = f2b(y);

        float ss = y * y;
#pragma unroll
        for (int off = 32; off > 0; off >>= 1)
            ss += __shfl_xor(ss, off);
        float inv = 1.0f / fmaxf(sqrtf(ss), 1e-12f);
        out[(size_t)row * 192 + out_col + o] = y * inv;
    }
}

// ---------------------------------------------------------------------------
// Fallback path (ws too small): atomic SpMM + separate dense, fp32.
// ---------------------------------------------------------------------------
__global__ __launch_bounds__(256) void spmm_atomic_kernel(
    const float* __restrict__ ego,
    const int*   __restrict__ rows,
    const int*   __restrict__ cols,
    const float* __restrict__ vals,
    float*       __restrict__ side,
    int nnz)
{
    long long i = (long long)blockIdx.x * blockDim.x + threadIdx.x;
    long long total = (long long)nnz * DIM;
    if (i >= total) return;
    int e = (int)(i >> 6);
    int d = (int)(i & 63);
    atomicAdd(side + ((size_t)rows[e] * DIM + d), vals[e] * ego[(size_t)cols[e] * DIM + d]);
}

template<bool WRITE_F32>
__global__ __launch_bounds__(256) void dense_norm_kernel(
    const float* __restrict__ ego_in,
    const float* __restrict__ side,
    const float* __restrict__ gw, const float* __restrict__ gb,
    const float* __restrict__ bw, const float* __restrict__ bb,
    float* __restrict__ ego_out,
    float* __restrict__ out, int out_col)
{
    __shared__ float s_lds[32][DIM];
    __shared__ float p_lds[32][DIM];

    const int o  = threadIdx.x & 63;
    const int wv = threadIdx.x >> 6;

    float w0[DIM], w1[DIM];
#pragma unroll
    for (int k4 = 0; k4 < DIM / 4; ++k4) {
        float4 a = *(const float4*)(gw + (size_t)o * DIM + k4 * 4);
        float4 b = *(const float4*)(bw + (size_t)o * DIM + k4 * 4);
        w0[4*k4+0] = a.x; w0[4*k4+1] = a.y; w0[4*k4+2] = a.z; w0[4*k4+3] = a.w;
        w1[4*k4+0] = b.x; w1[4*k4+1] = b.y; w1[4*k4+2] = b.z; w1[4*k4+3] = b.w;
    }
    const float bias = gb[o] + bb[o];

    for (int tile = blockIdx.x * 32; tile < N_NODES; tile += gridDim.x * 32) {
        int nmax = min(32, N_NODES - tile);
        __syncthreads();
        const float4* sd4 = (const float4*)side + (size_t)tile * 16;
        const float4* eg4 = (const float4*)ego_in + (size_t)tile * 16;
        float4* s4 = (float4*)&s_lds[0][0];
        float4* p4 = (float4*)&p_lds[0][0];
        for (int i = threadIdx.x; i < nmax * 16; i += 256) {
            float4 e = eg4[i], s = sd4[i];
            s4[i] = make_float4(s.x+e.x, s.y+e.y, s.z+e.z, s.w+e.w);
            p4[i] = make_float4(s.x*e.x, s.y*e.y, s.z*e.z, s.w*e.w);
        }
        __syncthreads();
        for (int n = wv; n < nmax; n += 4) {
            const float4* srow = (const float4*)&s_lds[n][0];
            const float4* prow = (const float4*)&p_lds[n][0];
            float a0 = bias, a1 = 0.f, a2 = 0.f, a3 = 0.f;
#pragma unroll
            for (int k4 = 0; k4 < 16; ++k4) {
                float4 sk = srow[k4];
                float4 pk = prow[k4];
                a0 = fmaf(sk.x, w0[4*k4+0], a0); a1 = fmaf(pk.x, w1[4*k4+0], a1);
                a2 = fmaf(sk.y, w0[4*k4+1], a2); a3 = fmaf(pk.y, w1[4*k4+1], a3);
                a0 = fmaf(sk.z, w0[4*k4+2], a0); a1 = fmaf(pk.z, w1[4*k4+2], a1);
                a2 = fmaf(sk.w, w0[4*k4+3], a2); a3 = fmaf(pk.w, w1[4*k4+3], a3);
            }
            float acc = (a0 + a1) + (a2 + a3);
            float y = acc > 0.f ? acc : 0.2f * acc;
            size_t node = (size_t)(tile + n);
            if (WRITE_F32) ego_out[node * DIM + o] = y;
            float ss = y * y;
#pragma unroll
            for (int off = 32; off > 0; off >>= 1)
                ss += __shfl_xor(ss, off);
            float inv = 1.0f / fmaxf(sqrtf(ss), 1e-12f);
            out[node * 192 + out_col + o] = y * inv;
        }
    }
}

__global__ __launch_bounds__(256) void copy_emb_kernel(
    const float4* __restrict__ emb, float4* __restrict__ out)
{
    int i = blockIdx.x * blockDim.x + threadIdx.x;
    if (i >= N_NODES * 16) return;
    int n = i >> 4, j = i & 15;
    out[(size_t)n * 48 + j] = emb[i];
}

extern "C" void kernel_launch(void* const* d_in, const int* in_sizes, int n_in,
                              void* d_out, int out_size, void* d_ws, size_t ws_size,
                              hipStream_t stream)
{
    const float* emb   = (const float*)d_in[0];
    const float* gc_w0 = (const float*)d_in[1];
    const float* gc_b0 = (const float*)d_in[2];
    const float* bi_w0 = (const float*)d_in[3];
    const float* bi_b0 = (const float*)d_in[4];
    const float* gc_w1 = (const float*)d_in[5];
    const float* gc_b1 = (const float*)d_in[6];
    const float* bi_w1 = (const float*)d_in[7];
    const float* bi_b1 = (const float*)d_in[8];
    const int*   rows  = (const int*)d_in[9];
    const int*   cols  = (const int*)d_in[10];
    const float* vals  = (const float*)d_in[11];
    const int    nnz   = in_sizes[9];

    float* out = (float*)d_out;

    const int nch = (nnz + CHUNK - 1) / CHUNK;            // chunks
    const int n2  = NB_B * nch;                           // hist entries
    const size_t hist_bytes = (size_t)n2 * sizeof(int);

    // ---- workspace layout ----
    char* ws = (char*)d_ws;
    size_t off = 0;
    auto alloc = [&](size_t bytes) { char* p = ws + off; off += (bytes + 63) & ~size_t(63); return p; };
    // region A: csr path = emb_b + ego1_b (bf16 tables); fallback = side (fp32)
    char* regionA = alloc((size_t)N_NODES * DIM * sizeof(float));
    ushort_t* emb_b  = (ushort_t*)regionA;
    ushort_t* ego1_b = emb_b + (size_t)N_NODES * DIM;
    float*    side   = (float*)regionA;
    int2* meta = (int2*)alloc((size_t)nnz * sizeof(int2));
    char* U = alloc(2 * ((hist_bytes + 63) & ~size_t(63)));  // build-phase hists
    int* histT = (int*)U;
    int* histA = (int*)(U + ((hist_bytes + 63) & ~size_t(63)));
    int* curT  = histT;                                   // reuse after transpose 1
    int* row_ptr = (int*)alloc((size_t)(N_NODES + 1) * sizeof(int));
    int* bsum    = (int*)alloc(2048 * sizeof(int));
    const bool csr_ok = (off <= ws_size) && (nnz <= 11000000);  // CAP headroom

    if (csr_ok) {
        // ---- bucketed CSR build ----
        binhist_kernel<<<nch, 256, 0, stream>>>(rows, histT, nnz);
        {   // histT[nch][NB_B] -> histA[NB_B][nch]
            dim3 g((NB_B + 31) / 32, (nch + 31) / 32);
            transpose_kernel<<<g, 256, 0, stream>>>(histT, histA, nch, NB_B);
        }
        const int nsb = (n2 + SCAN_B - 1) / SCAN_B;       // <= 2048
        scan1_kernel<<<nsb, 256, 0, stream>>>(histA, bsum, n2);
        scan2_kernel<<<1, 256, 0, stream>>>(bsum, nsb);
        scan3_kernel<<<(n2 + 255) / 256, 256, 0, stream>>>(histA, bsum, n2);
        {   // histA[NB_B][nch] (scanned) -> curT[nch][NB_B]
            dim3 g((nch + 31) / 32, (NB_B + 31) / 32);
            transpose_kernel<<<g, 256, 0, stream>>>(histA, curT, NB_B, nch);
        }
        binscatter_kernel<<<nch, 512, 0, stream>>>(rows, cols, vals, curT, meta, nnz);
        bucketfinal_kernel<<<NB_B, 256, 0, stream>>>(histA, meta, row_ptr, nnz, nch);

        // emb -> out[:,0:64] and bf16 table, one pass
        emb_prep_kernel<<<(N_NODES * 16 + 255) / 256, 256, 0, stream>>>(
            (const float4*)emb, (ushort4*)emb_b, (float4*)out);

        // ---- layer 0 (writes ego1_b table + out[:,64:128]) ----
        fused_layer_kernel<true><<<2048, 256, 0, stream>>>(
            (const uint4*)emb_b, row_ptr, meta, gc_w0, gc_b0, bi_w0, bi_b0,
            ego1_b, out, DIM);
        // ---- layer 1 (out[:,128:192]) ----
        fused_layer_kernel<false><<<2048, 256, 0, stream>>>(
            (const uint4*)ego1_b, row_ptr, meta, gc_w1, gc_b1, bi_w1, bi_b1,
            nullptr, out, 2 * DIM);
    } else {
        // ---- fallback: atomic SpMM + separate dense, fp32 ----
        float* ego1 = (float*)meta;   // nnz*8 B >= N*DIM*4 B
        const size_t side_bytes = (size_t)N_NODES * DIM * sizeof(float);
        const long long total = (long long)nnz * DIM;
        const int ab = (int)((total + 255) / 256);
        const int dense_blocks = (N_NODES + 31) / 32;
        hipMemsetAsync(side, 0, side_bytes, stream);
        spmm_atomic_kernel<<<ab, 256, 0, stream>>>(emb, rows, cols, vals, side, nnz);
        dense_norm_kernel<true><<<dense_blocks, 256, 0, stream>>>(
            emb, side, gc_w0, gc_b0, bi_w0, bi_b0, ego1, out, DIM);
        hipMemsetAsync(side, 0, side_bytes, stream);
        spmm_atomic_kernel<<<ab, 256, 0, stream>>>(ego1, rows, cols, vals, side, nnz);
        dense_norm_kernel<false><<<dense_blocks, 256, 0, stream>>>(
            ego1, side, gc_w1, gc_b1, bi_w1, bi_b1, nullptr, out, 2 * DIM);
        copy_emb_kernel<<<(N_NODES * 16 + 255) / 256, 256, 0, stream>>>(
            (const float4*)emb, (float4*)out);
    }
}

// Round 8
// 855.987 us; speedup vs baseline: 1.9201x; 1.9201x over previous
//
#include <hip/hip_runtime.h>
#include <hip/hip_bf16.h>

// NGCF forward, MI355X. Sizes fixed by the problem.
constexpr int N_NODES = 300000;   // N_USERS + N_ITEMS
constexpr int DIM = 64;

// Bucketed CSR build parameters
constexpr int CHUNK  = 8192;            // edges per binning block
constexpr int B_ROWS = 256;             // rows per bucket (bucket = row >> 8)
constexpr int NB_B   = (N_NODES + B_ROWS - 1) / B_ROWS;   // 1172 buckets
constexpr int CAP    = 12288;           // max edges/bucket in bucketfinal LDS
constexpr int SCAN_B = 4096;            // elements per scan1 block (16/thread)
constexpr int COL_MASK = (1 << 19) - 1; // col < 2^19 (300000 < 524288)

typedef unsigned short ushort_t;
typedef __attribute__((ext_vector_type(8))) short bf16x8;
typedef __attribute__((ext_vector_type(4))) float f32x4;

__device__ __forceinline__ float blo(unsigned u) { return __uint_as_float(u << 16); }
__device__ __forceinline__ float bhi(unsigned u) { return __uint_as_float(u & 0xffff0000u); }
__device__ __forceinline__ ushort_t f2b(float f) {            // fp32 -> bf16 (RNE)
    unsigned u = __float_as_uint(f);
    return (ushort_t)((u + 0x7fffu + ((u >> 16) & 1u)) >> 16);
}

// ---------------------------------------------------------------------------
// k1: per-chunk bucket histogram. histT[chunk][b] (coalesced write).
// ---------------------------------------------------------------------------
__global__ __launch_bounds__(256) void binhist_kernel(
    const int* __restrict__ rows, int* __restrict__ histT, int nnz)
{
    __shared__ int cnt[NB_B];
    for (int i = threadIdx.x; i < NB_B; i += 256) cnt[i] = 0;
    __syncthreads();
    int base = blockIdx.x * CHUNK;
#pragma unroll
    for (int k = 0; k < CHUNK / 256; ++k) {
        int e = base + k * 256 + threadIdx.x;
        if (e < nnz) atomicAdd(&cnt[rows[e] >> 8], 1);
    }
    __syncthreads();
    for (int b = threadIdx.x; b < NB_B; b += 256)
        histT[(size_t)blockIdx.x * NB_B + b] = cnt[b];
}

// 32x32 tiled transpose: in[R][C] -> out[C][R]
__global__ __launch_bounds__(256) void transpose_kernel(
    const int* __restrict__ in, int* __restrict__ out, int R, int C)
{
    __shared__ int tile[32][33];
    int c0 = blockIdx.x * 32, r0 = blockIdx.y * 32;
    int tx = threadIdx.x & 31, ty = threadIdx.x >> 5;
#pragma unroll
    for (int k = 0; k < 4; ++k) {
        int r = r0 + ty + k * 8, c = c0 + tx;
        if (r < R && c < C) tile[ty + k * 8][tx] = in[(size_t)r * C + c];
    }
    __syncthreads();
#pragma unroll
    for (int k = 0; k < 4; ++k) {
        int c = c0 + ty + k * 8, r = r0 + tx;
        if (c < C && r < R) out[(size_t)c * R + r] = tile[tx][ty + k * 8];
    }
}

// ---------------------------------------------------------------------------
// Exclusive scan over n elements (in place).
// ---------------------------------------------------------------------------
__global__ __launch_bounds__(256) void scan1_kernel(
    int* __restrict__ a, int* __restrict__ bsum, int n)
{
    __shared__ int tsum[256];
    int base = blockIdx.x * SCAN_B;
    int v[16];
    int s = 0;
#pragma unroll
    for (int k = 0; k < 16; ++k) {
        int i = base + threadIdx.x * 16 + k;
        v[k] = (i < n) ? a[i] : 0;
        s += v[k];
    }
    tsum[threadIdx.x] = s;
    __syncthreads();
    for (int off = 1; off < 256; off <<= 1) {
        int u = (threadIdx.x >= off) ? tsum[threadIdx.x - off] : 0;
        __syncthreads();
        tsum[threadIdx.x] += u;
        __syncthreads();
    }
    int excl = (threadIdx.x == 0) ? 0 : tsum[threadIdx.x - 1];
#pragma unroll
    for (int k = 0; k < 16; ++k) {
        int i = base + threadIdx.x * 16 + k;
        if (i < n) a[i] = excl;
        excl += v[k];
    }
    if (threadIdx.x == 255) bsum[blockIdx.x] = tsum[255];
}

__global__ __launch_bounds__(256) void scan2_kernel(int* bsum, int nb)   // nb <= 2048
{
    __shared__ int tsum[256];
    int v[8];
    int s = 0;
#pragma unroll
    for (int k = 0; k < 8; ++k) {
        int i = threadIdx.x * 8 + k;
        v[k] = (i < nb) ? bsum[i] : 0;
        s += v[k];
    }
    tsum[threadIdx.x] = s;
    __syncthreads();
    for (int off = 1; off < 256; off <<= 1) {
        int u = (threadIdx.x >= off) ? tsum[threadIdx.x - off] : 0;
        __syncthreads();
        tsum[threadIdx.x] += u;
        __syncthreads();
    }
    int excl = (threadIdx.x == 0) ? 0 : tsum[threadIdx.x - 1];
#pragma unroll
    for (int k = 0; k < 8; ++k) {
        int i = threadIdx.x * 8 + k;
        if (i < nb) bsum[i] = excl;
        excl += v[k];
    }
}

__global__ __launch_bounds__(256) void scan3_kernel(
    int* __restrict__ a, const int* __restrict__ bsum, int n)
{
    int i = blockIdx.x * 256 + threadIdx.x;
    if (i < n) a[i] += bsum[i >> 12];    // SCAN_B = 4096
}

// ---------------------------------------------------------------------------
// k5: binned scatter — LDS counting-sort of the chunk, then ordered flush.
// Payload packed: x = col | (local_row << 19), y = val bits.
// ---------------------------------------------------------------------------
__global__ __launch_bounds__(512) void binscatter_kernel(
    const int* __restrict__ rows, const int* __restrict__ cols,
    const float* __restrict__ vals, const int* __restrict__ curT,
    int2* __restrict__ meta, int nnz)
{
    __shared__ int2 cv[CHUNK];      // 64 KB  sorted payload
    __shared__ int  dst[CHUNK];     // 32 KB  global destination per slot
    __shared__ int  cnt[NB_B];      // hist, then per-bucket cursor
    __shared__ int  loc[NB_B];      // local exclusive offsets
    __shared__ int  gb[NB_B];       // global bases for this chunk
    __shared__ int  tsum[512];

    const int tid  = threadIdx.x;
    const int base = blockIdx.x * CHUNK;

    for (int b = tid; b < NB_B; b += 512) cnt[b] = 0;
    __syncthreads();

    int rb[16], pk[16], vb[16];
#pragma unroll
    for (int k = 0; k < 16; ++k) {
        int e = base + k * 512 + tid;
        if (e < nnz) {
            int r = rows[e];
            rb[k] = r >> 8;
            pk[k] = cols[e] | ((r & 255) << 19);
            vb[k] = __float_as_int(vals[e]);
            atomicAdd(&cnt[rb[k]], 1);
        } else rb[k] = -1;
    }
    __syncthreads();

    int i0 = tid * 3;
    int c0 = 0, c1 = 0, c2 = 0, s = 0;
    if (i0     < NB_B) { c0 = cnt[i0];     s += c0; }
    if (i0 + 1 < NB_B) { c1 = cnt[i0 + 1]; s += c1; }
    if (i0 + 2 < NB_B) { c2 = cnt[i0 + 2]; s += c2; }
    tsum[tid] = s;
    __syncthreads();
    for (int off = 1; off < 512; off <<= 1) {
        int u = (tid >= off) ? tsum[tid - off] : 0;
        __syncthreads();
        tsum[tid] += u;
        __syncthreads();
    }
    int ex = (tid == 0) ? 0 : tsum[tid - 1];
    if (i0     < NB_B) { loc[i0]     = ex; ex += c0; }
    if (i0 + 1 < NB_B) { loc[i0 + 1] = ex; ex += c1; }
    if (i0 + 2 < NB_B) { loc[i0 + 2] = ex; ex += c2; }
    __syncthreads();

    for (int b = tid; b < NB_B; b += 512) {
        gb[b]  = curT[(size_t)blockIdx.x * NB_B + b];
        cnt[b] = 0;
    }
    __syncthreads();

#pragma unroll
    for (int k = 0; k < 16; ++k) {
        if (rb[k] >= 0) {
            int b   = rb[k];
            int off = atomicAdd(&cnt[b], 1);
            int p   = loc[b] + off;
            cv[p]   = make_int2(pk[k], vb[k]);
            dst[p]  = gb[b] + off;
        }
    }
    __syncthreads();

    int n = min(nnz - base, CHUNK);
    for (int i = tid; i < n; i += 512)
        meta[dst[i]] = cv[i];
}

// ---------------------------------------------------------------------------
// k6: per-bucket finalize. Builds row_ptr, permutes payload in place.
// ---------------------------------------------------------------------------
__global__ __launch_bounds__(256) void bucketfinal_kernel(
    const int* __restrict__ histS,      // [NB_B][nch] scanned (bucket-major)
    int2* __restrict__ meta,
    int* __restrict__ row_ptr, int nnz, int nch)
{
    __shared__ int2 cv[CAP];            // 96 KB
    __shared__ int cnt[256], scn[256], cur[256];

    int b    = blockIdx.x;
    int base = histS[(size_t)b * nch];
    int end  = (b + 1 < gridDim.x) ? histS[(size_t)(b + 1) * nch] : nnz;
    int n    = min(end - base, CAP);

    cnt[threadIdx.x] = 0;
    __syncthreads();
    for (int i = threadIdx.x; i < n; i += 256) {
        int2 m = meta[base + i];
        cv[i] = m;
        atomicAdd(&cnt[(m.x >> 19) & 255], 1);
    }
    __syncthreads();
    int v = cnt[threadIdx.x];
    scn[threadIdx.x] = v;
    __syncthreads();
    for (int off = 1; off < 256; off <<= 1) {
        int u = (threadIdx.x >= off) ? scn[threadIdx.x - off] : 0;
        __syncthreads();
        scn[threadIdx.x] += u;
        __syncthreads();
    }
    int excl = scn[threadIdx.x] - v;

    int r0 = b * B_ROWS;
    int nr = min(B_ROWS, N_NODES - r0);
    if (threadIdx.x < nr) row_ptr[r0 + threadIdx.x] = base + excl;
    if (b == gridDim.x - 1 && threadIdx.x == 0) row_ptr[N_NODES] = nnz;

    cur[threadIdx.x] = excl;
    __syncthreads();
    for (int i = threadIdx.x; i < n; i += 256) {
        int2 m = cv[i];
        int d = atomicAdd(&cur[(m.x >> 19) & 255], 1);
        meta[base + d] = m;
    }
}

// ---------------------------------------------------------------------------
// emb prep: out[:,0:64] = emb AND bf16 table in one pass over emb.
// ---------------------------------------------------------------------------
__global__ __launch_bounds__(256) void emb_prep_kernel(
    const float4* __restrict__ emb, ushort4* __restrict__ tblB,
    float4* __restrict__ out)
{
    int i = blockIdx.x * 256 + threadIdx.x;
    if (i >= N_NODES * 16) return;
    float4 x = emb[i];
    int n = i >> 4, j = i & 15;
    out[(size_t)n * 48 + j] = x;
    ushort4 u;
    u.x = f2b(x.x); u.y = f2b(x.y); u.z = f2b(x.z); u.w = f2b(x.w);
    tblB[i] = u;
}

// ---------------------------------------------------------------------------
// CSR SpMM with bf16 gather table: one wave per row, 8 edge slots x 8
// dim-eighths, fp32 accumulate, no atomics. (round-6 version, VGPR=16,
// high occupancy — keep it that way for gather-latency hiding.)
// ---------------------------------------------------------------------------
__global__ __launch_bounds__(256) void spmm_csr_b_kernel(
    const uint4* __restrict__ ego_b,
    const int*   __restrict__ row_ptr,
    const int2*  __restrict__ meta,
    float*       __restrict__ side)
{
    int wid = (blockIdx.x * 256 + threadIdx.x) >> 6;
    if (wid >= N_NODES) return;
    int lane = threadIdx.x & 63;
    int g = lane >> 3;
    int q = lane & 7;

    int start = row_ptr[wid];
    int end   = row_ptr[wid + 1];

    float acc[8];
#pragma unroll
    for (int i = 0; i < 8; ++i) acc[i] = 0.f;

    for (int j = start + g; j < end; j += 8) {
        int2 m = meta[j];
        float v = __int_as_float(m.y);
        uint4 x = ego_b[(size_t)(m.x & COL_MASK) * 8 + q];
        acc[0] += v * blo(x.x); acc[1] += v * bhi(x.x);
        acc[2] += v * blo(x.y); acc[3] += v * bhi(x.y);
        acc[4] += v * blo(x.z); acc[5] += v * bhi(x.z);
        acc[6] += v * blo(x.w); acc[7] += v * bhi(x.w);
    }
#pragma unroll
    for (int off = 8; off <= 32; off <<= 1) {
#pragma unroll
        for (int i = 0; i < 8; ++i) acc[i] += __shfl_xor(acc[i], off);
    }
    if (g == 0) {
        float4* dst = (float4*)(side + (size_t)wid * DIM + q * 8);
        dst[0] = make_float4(acc[0], acc[1], acc[2], acc[3]);
        dst[1] = make_float4(acc[4], acc[5], acc[6], acc[7]);
    }
}

// ---------------------------------------------------------------------------
// MFMA dense layer: y = leaky(s@gw.T + gb + p@bw.T + bb), s=side+e, p=side*e.
// 64 nodes per block; 4 waves, each owns a 16-node sub-tile.
// v_mfma_f32_16x16x32_bf16: A row=lane%16, k=8*(lane/16)+elem;
// B col=lane%16, k=8*(lane/16)+elem; D col=lane&15, row=(lane>>4)*4+reg (m89).
// Weights held as 16 bf16x8 B-fragments in registers; s,p staged bf16 in LDS
// with +16B row pad (rows 144 B) to spread banks.
// ---------------------------------------------------------------------------
template<bool WRITE_TBL>
__global__ __launch_bounds__(256) void dense_mfma_kernel(
    const ushort_t* __restrict__ ego_b16,   // bf16 ego table [N][64]
    const float* __restrict__ side,
    const float* __restrict__ gw, const float* __restrict__ gb,
    const float* __restrict__ bw, const float* __restrict__ bb,
    ushort_t* __restrict__ tbl_out,         // bf16 ego out (layer 0)
    float* __restrict__ out, int out_col)
{
    __shared__ ushort_t s_lds[64][72];      // 9 KB (pad 8 bf16 = 16 B)
    __shared__ ushort_t p_lds[64][72];      // 9 KB

    const int tid  = threadIdx.x;
    const int lane = tid & 63;
    const int wv   = tid >> 6;
    const int lrow = lane & 15;
    const int kgrp = lane >> 4;

    // B-fragments (weights) + bias, loaded once
    bf16x8 wgf[4][2], wbf[4][2];
    float  biasv[4];
#pragma unroll
    for (int t = 0; t < 4; ++t) {
        int o = 16 * t + lrow;
#pragma unroll
        for (int h = 0; h < 2; ++h) {
            const float* pg = gw + (size_t)o * DIM + 32 * h + 8 * kgrp;
            const float* pb = bw + (size_t)o * DIM + 32 * h + 8 * kgrp;
            ushort_t tg[8], tb[8];
#pragma unroll
            for (int i = 0; i < 8; ++i) { tg[i] = f2b(pg[i]); tb[i] = f2b(pb[i]); }
            wgf[t][h] = *(const bf16x8*)tg;
            wbf[t][h] = *(const bf16x8*)tb;
        }
        biasv[t] = gb[o] + bb[o];
    }

    for (int tile0 = blockIdx.x * 64; tile0 < N_NODES; tile0 += gridDim.x * 64) {
        int nmax = min(64, N_NODES - tile0);
        __syncthreads();
        // ---- stage s,p (bf16) for 64 nodes: thread = (row, dim-quarter) ----
        {
            int r  = tid >> 2;
            int d0 = (tid & 3) * 16;
            if (r < nmax) {
                const float4* sp = (const float4*)(side + (size_t)(tile0 + r) * DIM + d0);
                const uint4*  ep = (const uint4*)(ego_b16 + (size_t)(tile0 + r) * DIM + d0);
                uint4 e0 = ep[0], e1 = ep[1];
                float4 s0 = sp[0], s1 = sp[1], s2 = sp[2], s3 = sp[3];
                float ev[16] = { blo(e0.x), bhi(e0.x), blo(e0.y), bhi(e0.y),
                                 blo(e0.z), bhi(e0.z), blo(e0.w), bhi(e0.w),
                                 blo(e1.x), bhi(e1.x), blo(e1.y), bhi(e1.y),
                                 blo(e1.z), bhi(e1.z), blo(e1.w), bhi(e1.w) };
                float sv[16] = { s0.x, s0.y, s0.z, s0.w, s1.x, s1.y, s1.z, s1.w,
                                 s2.x, s2.y, s2.z, s2.w, s3.x, s3.y, s3.z, s3.w };
                unsigned spk[8], ppk[8];
#pragma unroll
                for (int i = 0; i < 8; ++i) {
                    float a  = sv[2*i]   + ev[2*i];
                    float b2 = sv[2*i+1] + ev[2*i+1];
                    float c  = sv[2*i]   * ev[2*i];
                    float d  = sv[2*i+1] * ev[2*i+1];
                    spk[i] = ((unsigned)f2b(b2) << 16) | f2b(a);
                    ppk[i] = ((unsigned)f2b(d)  << 16) | f2b(c);
                }
                *(uint4*)&s_lds[r][d0]     = make_uint4(spk[0], spk[1], spk[2], spk[3]);
                *(uint4*)&s_lds[r][d0 + 8] = make_uint4(spk[4], spk[5], spk[6], spk[7]);
                *(uint4*)&p_lds[r][d0]     = make_uint4(ppk[0], ppk[1], ppk[2], ppk[3]);
                *(uint4*)&p_lds[r][d0 + 8] = make_uint4(ppk[4], ppk[5], ppk[6], ppk[7]);
            }
        }
        __syncthreads();

        // ---- compute: wave wv owns nodes tile0 + wv*16 .. +15 ----
        const int arow = wv * 16 + lrow;
        bf16x8 sf[2], pf[2];
        sf[0] = *(const bf16x8*)&s_lds[arow][8 * kgrp];
        sf[1] = *(const bf16x8*)&s_lds[arow][32 + 8 * kgrp];
        pf[0] = *(const bf16x8*)&p_lds[arow][8 * kgrp];
        pf[1] = *(const bf16x8*)&p_lds[arow][32 + 8 * kgrp];

        f32x4 acc[4];
#pragma unroll
        for (int t = 0; t < 4; ++t)
            acc[t] = (f32x4){biasv[t], biasv[t], biasv[t], biasv[t]};

#pragma unroll
        for (int h = 0; h < 2; ++h) {
#pragma unroll
            for (int t = 0; t < 4; ++t) {
                acc[t] = __builtin_amdgcn_mfma_f32_16x16x32_bf16(sf[h], wgf[t][h], acc[t], 0, 0, 0);
                acc[t] = __builtin_amdgcn_mfma_f32_16x16x32_bf16(pf[h], wbf[t][h], acc[t], 0, 0, 0);
            }
        }

        // ---- epilogue: leaky, row-norm (16-lane group reduce), stores ----
        float y[4][4];
        float ssr[4] = {0.f, 0.f, 0.f, 0.f};
#pragma unroll
        for (int t = 0; t < 4; ++t)
#pragma unroll
            for (int rg = 0; rg < 4; ++rg) {
                float v = acc[t][rg];
                v = v > 0.f ? v : 0.2f * v;
                y[t][rg] = v;
                ssr[rg] += v * v;
            }
#pragma unroll
        for (int off = 1; off <= 8; off <<= 1)
#pragma unroll
            for (int rg = 0; rg < 4; ++rg)
                ssr[rg] += __shfl_xor(ssr[rg], off);

#pragma unroll
        for (int rg = 0; rg < 4; ++rg) {
            int node = tile0 + wv * 16 + kgrp * 4 + rg;
            if (node < N_NODES) {
                float inv = 1.0f / fmaxf(sqrtf(ssr[rg]), 1e-12f);
                float* orow = out + (size_t)node * 192 + out_col;
#pragma unroll
                for (int t = 0; t < 4; ++t)
                    orow[t * 16 + lrow] = y[t][rg] * inv;
                if (WRITE_TBL) {
#pragma unroll
                    for (int t = 0; t < 4; ++t)
                        tbl_out[(size_t)node * DIM + t * 16 + lrow] = f2b(y[t][rg]);
                }
            }
        }
    }
}

// ---------------------------------------------------------------------------
// Fallback path (ws too small): atomic SpMM + fp32 dense.
// ---------------------------------------------------------------------------
__global__ __launch_bounds__(256) void spmm_atomic_kernel(
    const float* __restrict__ ego,
    const int*   __restrict__ rows,
    const int*   __restrict__ cols,
    const float* __restrict__ vals,
    float*       __restrict__ side,
    int nnz)
{
    long long i = (long long)blockIdx.x * blockDim.x + threadIdx.x;
    long long total = (long long)nnz * DIM;
    if (i >= total) return;
    int e = (int)(i >> 6);
    int d = (int)(i & 63);
    atomicAdd(side + ((size_t)rows[e] * DIM + d), vals[e] * ego[(size_t)cols[e] * DIM + d]);
}

template<bool WRITE_F32>
__global__ __launch_bounds__(256) void dense_norm_kernel(
    const float* __restrict__ ego_in,
    const float* __restrict__ side,
    const float* __restrict__ gw, const float* __restrict__ gb,
    const float* __restrict__ bw, const float* __restrict__ bb,
    float* __restrict__ ego_out,
    float* __restrict__ out, int out_col)
{
    __shared__ float s_lds[32][DIM];
    __shared__ float p_lds[32][DIM];

    const int o  = threadIdx.x & 63;
    const int wv = threadIdx.x >> 6;

    float w0[DIM], w1[DIM];
#pragma unroll
    for (int k4 = 0; k4 < DIM / 4; ++k4) {
        float4 a = *(const float4*)(gw + (size_t)o * DIM + k4 * 4);
        float4 b = *(const float4*)(bw + (size_t)o * DIM + k4 * 4);
        w0[4*k4+0] = a.x; w0[4*k4+1] = a.y; w0[4*k4+2] = a.z; w0[4*k4+3] = a.w;
        w1[4*k4+0] = b.x; w1[4*k4+1] = b.y; w1[4*k4+2] = b.z; w1[4*k4+3] = b.w;
    }
    const float bias = gb[o] + bb[o];

    for (int tile = blockIdx.x * 32; tile < N_NODES; tile += gridDim.x * 32) {
        int nmax = min(32, N_NODES - tile);
        __syncthreads();
        const float4* sd4 = (const float4*)side + (size_t)tile * 16;
        const float4* eg4 = (const float4*)ego_in + (size_t)tile * 16;
        float4* s4 = (float4*)&s_lds[0][0];
        float4* p4 = (float4*)&p_lds[0][0];
        for (int i = threadIdx.x; i < nmax * 16; i += 256) {
            float4 e = eg4[i], s = sd4[i];
            s4[i] = make_float4(s.x+e.x, s.y+e.y, s.z+e.z, s.w+e.w);
            p4[i] = make_float4(s.x*e.x, s.y*e.y, s.z*e.z, s.w*e.w);
        }
        __syncthreads();
        for (int n = wv; n < nmax; n += 4) {
            const float4* srow = (const float4*)&s_lds[n][0];
            const float4* prow = (const float4*)&p_lds[n][0];
            float a0 = bias, a1 = 0.f, a2 = 0.f, a3 = 0.f;
#pragma unroll
            for (int k4 = 0; k4 < 16; ++k4) {
                float4 sk = srow[k4];
                float4 pk = prow[k4];
                a0 = fmaf(sk.x, w0[4*k4+0], a0); a1 = fmaf(pk.x, w1[4*k4+0], a1);
                a2 = fmaf(sk.y, w0[4*k4+1], a2); a3 = fmaf(pk.y, w1[4*k4+1], a3);
                a0 = fmaf(sk.z, w0[4*k4+2], a0); a1 = fmaf(pk.z, w1[4*k4+2], a1);
                a2 = fmaf(sk.w, w0[4*k4+3], a2); a3 = fmaf(pk.w, w1[4*k4+3], a3);
            }
            float acc = (a0 + a1) + (a2 + a3);
            float y = acc > 0.f ? acc : 0.2f * acc;
            size_t node = (size_t)(tile + n);
            if (WRITE_F32) ego_out[node * DIM + o] = y;
            float ss = y * y;
#pragma unroll
            for (int off = 32; off > 0; off >>= 1)
                ss += __shfl_xor(ss, off);
            float inv = 1.0f / fmaxf(sqrtf(ss), 1e-12f);
            out[node * 192 + out_col + o] = y * inv;
        }
    }
}

__global__ __launch_bounds__(256) void copy_emb_kernel(
    const float4* __restrict__ emb, float4* __restrict__ out)
{
    int i = blockIdx.x * blockDim.x + threadIdx.x;
    if (i >= N_NODES * 16) return;
    int n = i >> 4, j = i & 15;
    out[(size_t)n * 48 + j] = emb[i];
}

extern "C" void kernel_launch(void* const* d_in, const int* in_sizes, int n_in,
                              void* d_out, int out_size, void* d_ws, size_t ws_size,
                              hipStream_t stream)
{
    const float* emb   = (const float*)d_in[0];
    const float* gc_w0 = (const float*)d_in[1];
    const float* gc_b0 = (const float*)d_in[2];
    const float* bi_w0 = (const float*)d_in[3];
    const float* bi_b0 = (const float*)d_in[4];
    const float* gc_w1 = (const float*)d_in[5];
    const float* gc_b1 = (const float*)d_in[6];
    const float* bi_w1 = (const float*)d_in[7];
    const float* bi_b1 = (const float*)d_in[8];
    const int*   rows  = (const int*)d_in[9];
    const int*   cols  = (const int*)d_in[10];
    const float* vals  = (const float*)d_in[11];
    const int    nnz   = in_sizes[9];

    float* out = (float*)d_out;

    const int nch = (nnz + CHUNK - 1) / CHUNK;            // chunks
    const int n2  = NB_B * nch;                           // hist entries
    const size_t hist_bytes = (size_t)n2 * sizeof(int);

    // ---- workspace layout ----
    char* ws = (char*)d_ws;
    size_t off = 0;
    auto alloc = [&](size_t bytes) { char* p = ws + off; off += (bytes + 63) & ~size_t(63); return p; };
    float* side = (float*)alloc((size_t)N_NODES * DIM * sizeof(float));
    // bf16 tables (csr path); dead in fallback
    ushort_t* emb_b  = (ushort_t*)alloc((size_t)N_NODES * DIM * sizeof(ushort_t));
    ushort_t* ego1_b = (ushort_t*)alloc((size_t)N_NODES * DIM * sizeof(ushort_t));
    int2* meta = (int2*)alloc((size_t)nnz * sizeof(int2));
    char* U = alloc(2 * ((hist_bytes + 63) & ~size_t(63)));  // build-phase hists
    int* histT = (int*)U;
    int* histA = (int*)(U + ((hist_bytes + 63) & ~size_t(63)));
    int* curT  = histT;                                   // reuse after transpose 1
    int* row_ptr = (int*)alloc((size_t)(N_NODES + 1) * sizeof(int));
    int* bsum    = (int*)alloc(2048 * sizeof(int));
    const bool csr_ok = (off <= ws_size) && (nnz <= 11000000);  // CAP headroom

    const int spmm_blocks  = (N_NODES * 64 + 255) / 256;
    const int dense_blocks = (N_NODES + 63) / 64;

    if (csr_ok) {
        // ---- bucketed CSR build ----
        binhist_kernel<<<nch, 256, 0, stream>>>(rows, histT, nnz);
        {   // histT[nch][NB_B] -> histA[NB_B][nch]
            dim3 g((NB_B + 31) / 32, (nch + 31) / 32);
            transpose_kernel<<<g, 256, 0, stream>>>(histT, histA, nch, NB_B);
        }
        const int nsb = (n2 + SCAN_B - 1) / SCAN_B;       // <= 2048
        scan1_kernel<<<nsb, 256, 0, stream>>>(histA, bsum, n2);
        scan2_kernel<<<1, 256, 0, stream>>>(bsum, nsb);
        scan3_kernel<<<(n2 + 255) / 256, 256, 0, stream>>>(histA, bsum, n2);
        {   // histA[NB_B][nch] (scanned) -> curT[nch][NB_B]
            dim3 g((nch + 31) / 32, (NB_B + 31) / 32);
            transpose_kernel<<<g, 256, 0, stream>>>(histA, curT, NB_B, nch);
        }
        binscatter_kernel<<<nch, 512, 0, stream>>>(rows, cols, vals, curT, meta, nnz);
        bucketfinal_kernel<<<NB_B, 256, 0, stream>>>(histA, meta, row_ptr, nnz, nch);

        // emb -> out[:,0:64] and bf16 table, one pass
        emb_prep_kernel<<<(N_NODES * 16 + 255) / 256, 256, 0, stream>>>(
            (const float4*)emb, (ushort4*)emb_b, (float4*)out);

        // ---- layer 0 ----
        spmm_csr_b_kernel<<<spmm_blocks, 256, 0, stream>>>(
            (const uint4*)emb_b, row_ptr, meta, side);
        dense_mfma_kernel<true><<<dense_blocks, 256, 0, stream>>>(
            emb_b, side, gc_w0, gc_b0, bi_w0, bi_b0, ego1_b, out, DIM);

        // ---- layer 1 ----
        spmm_csr_b_kernel<<<spmm_blocks, 256, 0, stream>>>(
            (const uint4*)ego1_b, row_ptr, meta, side);
        dense_mfma_kernel<false><<<dense_blocks, 256, 0, stream>>>(
            ego1_b, side, gc_w1, gc_b1, bi_w1, bi_b1, nullptr, out, 2 * DIM);
    } else {
        // ---- fallback: atomic SpMM + fp32 dense ----
        float* ego1 = (float*)meta;   // nnz*8 B >= N*DIM*4 B
        const size_t side_bytes = (size_t)N_NODES * DIM * sizeof(float);
        const long long total = (long long)nnz * DIM;
        const int ab = (int)((total + 255) / 256);
        const int db = (N_NODES + 31) / 32;
        hipMemsetAsync(side, 0, side_bytes, stream);
        spmm_atomic_kernel<<<ab, 256, 0, stream>>>(emb, rows, cols, vals, side, nnz);
        dense_norm_kernel<true><<<db, 256, 0, stream>>>(
            emb, side, gc_w0, gc_b0, bi_w0, bi_b0, ego1, out, DIM);
        hipMemsetAsync(side, 0, side_bytes, stream);
        spmm_atomic_kernel<<<ab, 256, 0, stream>>>(ego1, rows, cols, vals, side, nnz);
        dense_norm_kernel<false><<<db, 256, 0, stream>>>(
            ego1, side, gc_w1, gc_b1, bi_w1, bi_b1, nullptr, out, 2 * DIM);
        copy_emb_kernel<<<(N_NODES * 16 + 255) / 256, 256, 0, stream>>>(
            (const float4*)emb, (float4*)out);
    }
}